// Round 9
// baseline (130.417 us; speedup 1.0000x reference)
//
#include <hip/hip_runtime.h>

typedef unsigned short u16;
typedef u16 u16x8 __attribute__((ext_vector_type(8)));
typedef __bf16 bf16x8 __attribute__((ext_vector_type(8)));
typedef float f32x4 __attribute__((ext_vector_type(4)));

#define EMB 1024
#define TT 2048
#define BB 2
#define NHEADS 16
#define HD 64
#define MTOT (BB * TT)  // 4096

// ---------- helpers ----------
__device__ __forceinline__ u16 cvt(float f) {  // native f32->bf16 (RTNE)
  return __builtin_bit_cast(u16, (__bf16)f);
}

__device__ __forceinline__ bf16x8 asbf(u16x8 v) {
  return __builtin_bit_cast(bf16x8, v);
}

__device__ __forceinline__ void gload16(const void* g, void* l) {
  __builtin_amdgcn_global_load_lds(
      (const __attribute__((address_space(1))) void*)g,
      (__attribute__((address_space(3))) void*)l, 16, 0, 0);
}

// ---------- fused prep: x->bf16 + 4x W transpose->bf16, one launch ----------
__global__ __launch_bounds__(256) void k_prep(
    const float* __restrict__ x, u16* __restrict__ xb,
    const float* __restrict__ W0, const float* __restrict__ W1,
    const float* __restrict__ W2, const float* __restrict__ W3,
    u16* __restrict__ T0, u16* __restrict__ T1, u16* __restrict__ T2,
    u16* __restrict__ T3) {
  __shared__ float tile[32][33];
  const int bid = blockIdx.x;
  const int tid = threadIdx.x;
  if (bid >= 4096) {  // x conversion: 2048 blocks x 2048 elems
    int i = (bid - 4096) * 256 + tid;
    float4 a = ((const float4*)x)[i * 2];
    float4 b = ((const float4*)x)[i * 2 + 1];
    u16x8 o;
    o[0] = cvt(a.x); o[1] = cvt(a.y); o[2] = cvt(a.z); o[3] = cvt(a.w);
    o[4] = cvt(b.x); o[5] = cvt(b.y); o[6] = cvt(b.z); o[7] = cvt(b.w);
    ((u16x8*)xb)[i] = o;
    return;
  }
  const int z = bid >> 10;  // which W
  const float* __restrict__ W = (z == 0) ? W0 : (z == 1) ? W1 : (z == 2) ? W2 : W3;
  u16* __restrict__ Wt = (z == 0) ? T0 : (z == 1) ? T1 : (z == 2) ? T2 : T3;
  const int b = bid & 1023;
  const int bx = (b & 31) * 32, by = (b >> 5) * 32;
  const int tx = tid & 31;
  const int ty = tid >> 5;  // 0..7
#pragma unroll
  for (int r = ty; r < 32; r += 8) tile[r][tx] = W[(by + r) * EMB + bx + tx];
  __syncthreads();
  // vectorized transposed store: each thread packs 2 cols into one dword
  const int tx2 = tid & 15;
  const int ty2 = tid >> 4;  // 0..15
#pragma unroll
  for (int r = ty2; r < 32; r += 16) {
    unsigned v = (unsigned)cvt(tile[2 * tx2][r]) |
                 ((unsigned)cvt(tile[2 * tx2 + 1][r]) << 16);
    *(unsigned*)&Wt[(bx + r) * EMB + by + 2 * tx2] = v;
  }
}

// ---------- fused QKV GEMM (BK=64, swizzled LDS staging) ----------
__global__ __launch_bounds__(256) void k_gemm_qkv(
    const u16* __restrict__ xb, const u16* __restrict__ WqT,
    const u16* __restrict__ WkT, const u16* __restrict__ WvT,
    const float* __restrict__ bq, const float* __restrict__ bk,
    const float* __restrict__ bv, u16* __restrict__ Q, u16* __restrict__ K,
    u16* __restrict__ Vt) {
  __shared__ u16 Al[128 * 64];  // 16 KB, 128B rows, XOR-swizzled chunks
  __shared__ u16 Bl[128 * 64];
  const int tid = threadIdx.x;
  const int lane = tid & 63;
  const int w = tid >> 6;
  const int wr = w >> 1, wc = w & 1;
  const int lr = lane & 15, lg = lane >> 4;
  const int m0 = blockIdx.x * 128;
  const int nb = blockIdx.y;           // 0..23
  const int seg = nb >> 3;             // 0=Q 1=K 2=V
  const int n0 = (nb & 7) * 128;
  const u16* __restrict__ Bt = (seg == 0) ? WqT : (seg == 1) ? WkT : WvT;
  const float* __restrict__ bias = (seg == 0) ? bq : (seg == 1) ? bk : bv;

  f32x4 acc[4][4];
#pragma unroll
  for (int i = 0; i < 4; i++)
#pragma unroll
    for (int j = 0; j < 4; j++) acc[i][j] = (f32x4){0.f, 0.f, 0.f, 0.f};

  // staging: unit u = tid + 256m -> row (tid>>3)+32m, phys chunk tid&7.
  // Pre-swizzled source chunk sc = (tid&7)^g(row); g invariant under +32m.
  const int srow = tid >> 3;                                    // 0..31
  const int sgz = ((tid >> 3) & 3) | (((tid >> 6) & 1) << 2);   // g(row)
  const int sc = (tid & 7) ^ sgz;
  const u16* ga0 = xb + (m0 + srow) * EMB + sc * 8;
  const u16* gb0 = Bt + (n0 + srow) * EMB + sc * 8;
  char* la0 = (char*)Al + w * 1024;    // wave-uniform LDS base
  char* lb0 = (char*)Bl + w * 1024;
  // fragment-read swizzle: g(row)=(lr&3)|(((lr>>3)&1)<<2) for all row-blocks
  const int gfr = (lr & 3) | (((lr >> 3) & 1) << 2);

  for (int k0 = 0; k0 < EMB; k0 += 64) {
#pragma unroll
    for (int m = 0; m < 4; m++) {
      gload16(ga0 + (32 * m) * EMB + k0, la0 + m * 4096);
      gload16(gb0 + (32 * m) * EMB + k0, lb0 + m * 4096);
    }
    __syncthreads();
    u16x8 af[4][2], bfr[4][2];
#pragma unroll
    for (int hh = 0; hh < 2; hh++) {
      const int pc = ((hh * 4 + lg) ^ gfr) * 16;
#pragma unroll
      for (int mi = 0; mi < 4; mi++)
        af[mi][hh] =
            *(const u16x8*)((char*)Al + (wr * 64 + mi * 16 + lr) * 128 + pc);
#pragma unroll
      for (int ni = 0; ni < 4; ni++)
        bfr[ni][hh] =
            *(const u16x8*)((char*)Bl + (wc * 64 + ni * 16 + lr) * 128 + pc);
    }
#pragma unroll
    for (int hh = 0; hh < 2; hh++)
#pragma unroll
      for (int mi = 0; mi < 4; mi++)
#pragma unroll
        for (int ni = 0; ni < 4; ni++)
          acc[mi][ni] = __builtin_amdgcn_mfma_f32_16x16x32_bf16(
              asbf(af[mi][hh]), asbf(bfr[ni][hh]), acc[mi][ni], 0, 0, 0);
    __syncthreads();
  }

#pragma unroll
  for (int mi = 0; mi < 4; mi++) {
    const int lmb = wr * 64 + mi * 16 + lg * 4;
#pragma unroll
    for (int ni = 0; ni < 4; ni++) {
      const int ln = wc * 64 + ni * 16 + lr;
      const int n = n0 + ln;
      const float bv_ = bias[n];
      const int h = n >> 6, d = n & 63;
#pragma unroll
      for (int r = 0; r < 4; r++) {
        const int m = m0 + lmb + r;
        const int b = m >> 11, t = m & 2047;
        float v = acc[mi][ni][r] + bv_;
        if (seg == 0) {
          v *= 0.18033688011f;  // (1/sqrt(64)) * log2(e): exp2-domain scores
          Q[(((b * NHEADS + h) * TT) + t) * HD + d] = cvt(v);
        } else if (seg == 1) {
          K[(((b * NHEADS + h) * TT) + t) * HD + d] = cvt(v);
        } else {
          Vt[(((b * NHEADS + h) * HD) + d) * TT + t] = cvt(v);
        }
      }
    }
  }
}

// ---------- causal flash attention ----------
// 256-thr blocks (4 waves), 32-row q-block pairing: waves 0-1 hi=63-pair,
// waves 2-3 lo=pair (uniform 33 tile-computes/block). Grid 32x32 = 1024
// blocks, LDS 32KB -> 4 blocks/CU (4 independent barrier domains hide the
// per-iteration vmcnt drain). Swapped QK^T in-register P; defer-max; exp2.
__global__ __launch_bounds__(256) void k_attn(const u16* __restrict__ Q,
                                              const u16* __restrict__ Kg,
                                              const u16* __restrict__ Vt,
                                              u16* __restrict__ AO) {
  __shared__ u16 Kl[2][64 * 64];   // 8KB x2
  __shared__ u16 Vl[2][64 * 64];   // 8KB x2
  const int tid = threadIdx.x;
  const int lane = tid & 63;
  const int w = tid >> 6;          // 0..3
  const int lr = lane & 15, lg = lane >> 4;
  const int bh = blockIdx.x;       // 0..31
  const int pair = blockIdx.y;     // 0..31; pair 0 dispatches first (longest)
  const int lo = pair, hi = 63 - pair;     // 32-row q-block indices
  const int b32 = (w < 2) ? hi : lo;       // this wave's 32-row q-block
  const int myend = b32 >> 1;              // last 64-col k-tile index
  const int q0 = b32 * 32 + (w & 1) * 16;
  const u16* __restrict__ Qh = Q + bh * TT * HD;
  const u16* __restrict__ Kh = Kg + bh * TT * HD;
  const u16* __restrict__ Vh = Vt + bh * HD * TT;

  // staging: thread t covers rows t>>3 and (t>>3)+32, phys chunk t&7.
  // sc = (t&7) ^ g(row); g(row)=(row&3)|(((row>>3)&1)<<2) invariant at +32.
  const int srow = tid >> 3;  // 0..31
  const int sgz = ((tid >> 3) & 3) | (((tid >> 6) & 1) << 2);
  const int sc = (tid & 7) ^ sgz;

  u16x8 qf[2];
  qf[0] = *(const u16x8*)&Qh[(q0 + lr) * HD + lg * 8];
  qf[1] = *(const u16x8*)&Qh[(q0 + lr) * HD + 32 + lg * 8];

  f32x4 accO[4];
#pragma unroll
  for (int i = 0; i < 4; i++) accO[i] = (f32x4){0.f, 0.f, 0.f, 0.f};
  float mst = -__builtin_inff();  // per-lane: running max of row q0+lr
  float lsum = 0.f;               // per-lane partial denominator

  const int nkt = (hi >> 1) + 1;  // block-uniform loop count

  gload16(Kh + srow * HD + sc * 8, (char*)Kl[0] + w * 1024);
  gload16(Kh + (srow + 32) * HD + sc * 8, (char*)Kl[0] + w * 1024 + 4096);
  gload16(Vh + srow * TT + sc * 8, (char*)Vl[0] + w * 1024);
  gload16(Vh + (srow + 32) * TT + sc * 8, (char*)Vl[0] + w * 1024 + 4096);
  __syncthreads();  // drains vmcnt

  for (int kt = 0; kt < nkt; ++kt) {
    const int k0 = kt * 64;
    const int cur = kt & 1;
    if (kt + 1 < nkt) {  // issue next-tile loads BEFORE compute (2-phase)
      const int kn = k0 + 64;
      char* kd = (char*)Kl[cur ^ 1] + w * 1024;
      char* vd = (char*)Vl[cur ^ 1] + w * 1024;
      gload16(Kh + (kn + srow) * HD + sc * 8, kd);
      gload16(Kh + (kn + srow + 32) * HD + sc * 8, kd + 4096);
      gload16(Vh + srow * TT + kn + sc * 8, vd);
      gload16(Vh + (srow + 32) * TT + kn + sc * 8, vd + 4096);
    }
    if (kt <= myend) {  // wave-uniform: lo-waves idle past their diagonal
      const char* Kc = (const char*)Kl[cur];
      const char* Vc = (const char*)Vl[cur];

      f32x4 s[4];
#pragma unroll
      for (int n = 0; n < 4; n++) s[n] = (f32x4){0.f, 0.f, 0.f, 0.f};
      __builtin_amdgcn_s_setprio(1);
#pragma unroll
      for (int n = 0; n < 4; n++) {
        // permuted K-row: lane's 16 score cols == PV A-frag slots
        const int kr =
            (lr & 3) + ((n & 1) << 2) + ((lr >> 2) << 3) + ((n >> 1) << 5);
        const int gg = (kr & 3) | (((kr >> 3) & 1) << 2);
#pragma unroll
        for (int dh = 0; dh < 2; dh++) {
          const int bo = ((dh * 4 + lg) ^ gg) << 4;
          u16x8 kf = *(const u16x8*)(Kc + kr * 128 + bo);
          s[n] = __builtin_amdgcn_mfma_f32_16x16x32_bf16(asbf(kf), asbf(qf[dh]),
                                                         s[n], 0, 0, 0);
        }
      }
      __builtin_amdgcn_s_setprio(0);
      if (kt == myend) {  // diagonal tile: causal mask (col > my q-row)
        const int rowq = q0 + lr;
#pragma unroll
        for (int n = 0; n < 4; n++) {
          const int cb = k0 + ((n & 1) << 2) + (lg << 3) + ((n >> 1) << 5);
#pragma unroll
          for (int r = 0; r < 4; r++)
            if (cb + r > rowq) s[n][r] = -__builtin_inff();
        }
      }
      // lane-local row max over this tile's 16 cols
      float m01 = fmaxf(fmaxf(s[0][0], s[0][1]), fmaxf(s[0][2], s[0][3]));
      float m1 = fmaxf(fmaxf(s[1][0], s[1][1]), fmaxf(s[1][2], s[1][3]));
      float m2 = fmaxf(fmaxf(s[2][0], s[2][1]), fmaxf(s[2][2], s[2][3]));
      float m3 = fmaxf(fmaxf(s[3][0], s[3][1]), fmaxf(s[3][2], s[3][3]));
      float lmax = fmaxf(fmaxf(m01, m1), fmaxf(m2, m3));
      // defer-max (log2 domain, THR=11 bits). -inf tile0 forces rescale.
      if (!__all(lmax - mst <= 11.0f)) {
        float rm = lmax;
        rm = fmaxf(rm, __shfl_xor(rm, 16));
        rm = fmaxf(rm, __shfl_xor(rm, 32));
        float mnew = fmaxf(mst, rm);
        float corr = exp2f(mst - mnew);
        lsum *= corr;
        mst = mnew;
#pragma unroll
        for (int r = 0; r < 4; r++) {  // corr for accO's q-row (lg*4+r)
          float ca = __shfl(corr, 20 * lg + r);
#pragma unroll
          for (int dt = 0; dt < 4; dt++) accO[dt][r] *= ca;
        }
      }
      // P in-register: p[n][r] are exactly PV A-frag slots
      float p[4][4];
      float ls = 0.f;
#pragma unroll
      for (int n = 0; n < 4; n++)
#pragma unroll
        for (int r = 0; r < 4; r++) {
          p[n][r] = exp2f(s[n][r] - mst);
          ls += p[n][r];
        }
      lsum += ls;
      u16x8 a1, a2;
#pragma unroll
      for (int r = 0; r < 4; r++) {
        a1[r] = cvt(p[0][r]);
        a1[4 + r] = cvt(p[1][r]);
        a2[r] = cvt(p[2][r]);
        a2[4 + r] = cvt(p[3][r]);
      }
      __builtin_amdgcn_s_setprio(1);
#pragma unroll
      for (int dt = 0; dt < 4; dt++) {
        const int row = dt * 16 + lr;
        const int gg = (row & 3) | (((row >> 3) & 1) << 2);
        const int bo0 = ((lg ^ gg) << 4);
        const int bo1 = (((4 + lg) ^ gg) << 4);
        u16x8 vf0 = *(const u16x8*)(Vc + row * 128 + bo0);
        u16x8 vf1 = *(const u16x8*)(Vc + row * 128 + bo1);
        accO[dt] = __builtin_amdgcn_mfma_f32_16x16x32_bf16(asbf(a1), asbf(vf0),
                                                           accO[dt], 0, 0, 0);
        accO[dt] = __builtin_amdgcn_mfma_f32_16x16x32_bf16(asbf(a2), asbf(vf1),
                                                           accO[dt], 0, 0, 0);
      }
      __builtin_amdgcn_s_setprio(0);
    }
    __syncthreads();  // drains vmcnt: next buf staged; cur free to overwrite
  }
  // denominator: reduce the 4 lanes sharing this q-row, then redistribute
  float t = lsum;
  t += __shfl_xor(t, 16);
  t += __shfl_xor(t, 32);
  float rinv = 1.0f / t;
  float ra[4];
#pragma unroll
  for (int r = 0; r < 4; r++) ra[r] = __shfl(rinv, 20 * lg + r);
  const int b = bh >> 4, h = bh & 15;
#pragma unroll
  for (int dt = 0; dt < 4; dt++)
#pragma unroll
    for (int r = 0; r < 4; r++) {
      const int row = q0 + lg * 4 + r;
      const int d = h * 64 + dt * 16 + lr;
      AO[(b * TT + row) * EMB + d] = cvt(accO[dt][r] * ra[r]);
    }
}

// ---------- output projection GEMM (BK=64, fp32 out + bias) ----------
__global__ __launch_bounds__(256) void k_gemm_out(const u16* __restrict__ AO,
                                                  const u16* __restrict__ WoT,
                                                  const float* __restrict__ bo,
                                                  float* __restrict__ out) {
  __shared__ u16 Al[128 * 64];
  __shared__ u16 Bl[128 * 64];
  const int tid = threadIdx.x;
  const int lane = tid & 63;
  const int w = tid >> 6;
  const int wr = w >> 1, wc = w & 1;
  const int lr = lane & 15, lg = lane >> 4;
  const int m0 = blockIdx.x * 128;
  const int n0 = blockIdx.y * 128;

  f32x4 acc[4][4];
#pragma unroll
  for (int i = 0; i < 4; i++)
#pragma unroll
    for (int j = 0; j < 4; j++) acc[i][j] = (f32x4){0.f, 0.f, 0.f, 0.f};

  const int srow = tid >> 3;
  const int sgz = ((tid >> 3) & 3) | (((tid >> 6) & 1) << 2);
  const int sc = (tid & 7) ^ sgz;
  const u16* ga0 = AO + (m0 + srow) * EMB + sc * 8;
  const u16* gb0 = WoT + (n0 + srow) * EMB + sc * 8;
  char* la0 = (char*)Al + w * 1024;
  char* lb0 = (char*)Bl + w * 1024;
  const int gfr = (lr & 3) | (((lr >> 3) & 1) << 2);

  for (int k0 = 0; k0 < EMB; k0 += 64) {
#pragma unroll
    for (int m = 0; m < 4; m++) {
      gload16(ga0 + (32 * m) * EMB + k0, la0 + m * 4096);
      gload16(gb0 + (32 * m) * EMB + k0, lb0 + m * 4096);
    }
    __syncthreads();
    u16x8 af[4][2], bfr[4][2];
#pragma unroll
    for (int hh = 0; hh < 2; hh++) {
      const int pc = ((hh * 4 + lg) ^ gfr) * 16;
#pragma unroll
      for (int mi = 0; mi < 4; mi++)
        af[mi][hh] =
            *(const u16x8*)((char*)Al + (wr * 64 + mi * 16 + lr) * 128 + pc);
#pragma unroll
      for (int ni = 0; ni < 4; ni++)
        bfr[ni][hh] =
            *(const u16x8*)((char*)Bl + (wc * 64 + ni * 16 + lr) * 128 + pc);
    }
#pragma unroll
    for (int hh = 0; hh < 2; hh++)
#pragma unroll
      for (int mi = 0; mi < 4; mi++)
#pragma unroll
        for (int ni = 0; ni < 4; ni++)
          acc[mi][ni] = __builtin_amdgcn_mfma_f32_16x16x32_bf16(
              asbf(af[mi][hh]), asbf(bfr[ni][hh]), acc[mi][ni], 0, 0, 0);
    __syncthreads();
  }

#pragma unroll
  for (int mi = 0; mi < 4; mi++) {
    const int lmb = wr * 64 + mi * 16 + lg * 4;
#pragma unroll
    for (int ni = 0; ni < 4; ni++) {
      const int ln = wc * 64 + ni * 16 + lr;
      const int n = n0 + ln;
      const float bv_ = bo[n];
#pragma unroll
      for (int r = 0; r < 4; r++) {
        const int m = m0 + lmb + r;
        out[m * EMB + n] = acc[mi][ni][r] + bv_;
      }
    }
  }
}

// ---------- launch ----------
extern "C" void kernel_launch(void* const* d_in, const int* in_sizes, int n_in,
                              void* d_out, int out_size, void* d_ws,
                              size_t ws_size, hipStream_t stream) {
  const float* x = (const float*)d_in[0];
  const float* Wq = (const float*)d_in[1];
  const float* bq = (const float*)d_in[2];
  const float* Wk = (const float*)d_in[3];
  const float* bk = (const float*)d_in[4];
  const float* Wv = (const float*)d_in[5];
  const float* bv = (const float*)d_in[6];
  const float* Wo = (const float*)d_in[7];
  const float* bo = (const float*)d_in[8];
  float* out = (float*)d_out;

  char* ws = (char*)d_ws;
  u16* xb = (u16*)ws;                      // 8 MB (reused as AO)
  u16* WqT = (u16*)(ws + (8u << 20));      // 2 MB
  u16* WkT = (u16*)(ws + (10u << 20));     // 2 MB
  u16* WvT = (u16*)(ws + (12u << 20));     // 2 MB
  u16* WoT = (u16*)(ws + (14u << 20));     // 2 MB
  u16* Qb = (u16*)(ws + (16u << 20));      // 8 MB
  u16* Kb = (u16*)(ws + (24u << 20));      // 8 MB
  u16* Vtb = (u16*)(ws + (32u << 20));     // 8 MB (total 40 MB)
  u16* AO = xb;

  k_prep<<<6144, 256, 0, stream>>>(x, xb, Wq, Wk, Wv, Wo, WqT, WkT, WvT, WoT);
  k_gemm_qkv<<<dim3(32, 24), 256, 0, stream>>>(xb, WqT, WkT, WvT, bq, bk, bv,
                                               Qb, Kb, Vtb);
  k_attn<<<dim3(32, 32), 256, 0, stream>>>(Qb, Kb, Vtb, AO);
  k_gemm_out<<<dim3(32, 8), 256, 0, stream>>>(AO, WoT, bo, out);
}

// Round 10
// 118.526 us; speedup vs baseline: 1.1003x; 1.1003x over previous
//
#include <hip/hip_runtime.h>

typedef unsigned short u16;
typedef u16 u16x8 __attribute__((ext_vector_type(8)));
typedef __bf16 bf16x8 __attribute__((ext_vector_type(8)));
typedef float f32x4 __attribute__((ext_vector_type(4)));

#define EMB 1024
#define TT 2048
#define BB 2
#define NHEADS 16
#define HD 64
#define MTOT (BB * TT)  // 4096

// ---------- helpers ----------
__device__ __forceinline__ u16 cvt(float f) {  // native f32->bf16 (RTNE)
  return __builtin_bit_cast(u16, (__bf16)f);
}

__device__ __forceinline__ bf16x8 asbf(u16x8 v) {
  return __builtin_bit_cast(bf16x8, v);
}

__device__ __forceinline__ void gload16(const void* g, void* l) {
  __builtin_amdgcn_global_load_lds(
      (const __attribute__((address_space(1))) void*)g,
      (__attribute__((address_space(3))) void*)l, 16, 0, 0);
}

// ---------- fused prep: x->bf16 + 4x W transpose->bf16, one launch ----------
__global__ __launch_bounds__(256) void k_prep(
    const float* __restrict__ x, u16* __restrict__ xb,
    const float* __restrict__ W0, const float* __restrict__ W1,
    const float* __restrict__ W2, const float* __restrict__ W3,
    u16* __restrict__ T0, u16* __restrict__ T1, u16* __restrict__ T2,
    u16* __restrict__ T3) {
  __shared__ float tile[32][33];
  const int bid = blockIdx.x;
  const int tid = threadIdx.x;
  if (bid >= 4096) {  // x conversion: 2048 blocks x 2048 elems
    int i = (bid - 4096) * 256 + tid;
    float4 a = ((const float4*)x)[i * 2];
    float4 b = ((const float4*)x)[i * 2 + 1];
    u16x8 o;
    o[0] = cvt(a.x); o[1] = cvt(a.y); o[2] = cvt(a.z); o[3] = cvt(a.w);
    o[4] = cvt(b.x); o[5] = cvt(b.y); o[6] = cvt(b.z); o[7] = cvt(b.w);
    ((u16x8*)xb)[i] = o;
    return;
  }
  const int z = bid >> 10;  // which W
  const float* __restrict__ W = (z == 0) ? W0 : (z == 1) ? W1 : (z == 2) ? W2 : W3;
  u16* __restrict__ Wt = (z == 0) ? T0 : (z == 1) ? T1 : (z == 2) ? T2 : T3;
  const int b = bid & 1023;
  const int bx = (b & 31) * 32, by = (b >> 5) * 32;
  const int tx = tid & 31;
  const int ty = tid >> 5;  // 0..7
#pragma unroll
  for (int r = ty; r < 32; r += 8) tile[r][tx] = W[(by + r) * EMB + bx + tx];
  __syncthreads();
  // vectorized transposed store: each thread packs 2 cols into one dword
  const int tx2 = tid & 15;
  const int ty2 = tid >> 4;  // 0..15
#pragma unroll
  for (int r = ty2; r < 32; r += 16) {
    unsigned v = (unsigned)cvt(tile[2 * tx2][r]) |
                 ((unsigned)cvt(tile[2 * tx2 + 1][r]) << 16);
    *(unsigned*)&Wt[(bx + r) * EMB + by + 2 * tx2] = v;
  }
}

// ---------- fused QKV GEMM (BK=64, swizzled LDS staging) ----------
__global__ __launch_bounds__(256) void k_gemm_qkv(
    const u16* __restrict__ xb, const u16* __restrict__ WqT,
    const u16* __restrict__ WkT, const u16* __restrict__ WvT,
    const float* __restrict__ bq, const float* __restrict__ bk,
    const float* __restrict__ bv, u16* __restrict__ Q, u16* __restrict__ K,
    u16* __restrict__ Vt) {
  __shared__ u16 Al[128 * 64];  // 16 KB, 128B rows, XOR-swizzled chunks
  __shared__ u16 Bl[128 * 64];
  const int tid = threadIdx.x;
  const int lane = tid & 63;
  const int w = tid >> 6;
  const int wr = w >> 1, wc = w & 1;
  const int lr = lane & 15, lg = lane >> 4;
  const int m0 = blockIdx.x * 128;
  const int nb = blockIdx.y;           // 0..23
  const int seg = nb >> 3;             // 0=Q 1=K 2=V
  const int n0 = (nb & 7) * 128;
  const u16* __restrict__ Bt = (seg == 0) ? WqT : (seg == 1) ? WkT : WvT;
  const float* __restrict__ bias = (seg == 0) ? bq : (seg == 1) ? bk : bv;

  f32x4 acc[4][4];
#pragma unroll
  for (int i = 0; i < 4; i++)
#pragma unroll
    for (int j = 0; j < 4; j++) acc[i][j] = (f32x4){0.f, 0.f, 0.f, 0.f};

  const int srow = tid >> 3;                                    // 0..31
  const int sgz = ((tid >> 3) & 3) | (((tid >> 6) & 1) << 2);   // g(row)
  const int sc = (tid & 7) ^ sgz;
  const u16* ga0 = xb + (m0 + srow) * EMB + sc * 8;
  const u16* gb0 = Bt + (n0 + srow) * EMB + sc * 8;
  char* la0 = (char*)Al + w * 1024;    // wave-uniform LDS base
  char* lb0 = (char*)Bl + w * 1024;
  const int gfr = (lr & 3) | (((lr >> 3) & 1) << 2);

  for (int k0 = 0; k0 < EMB; k0 += 64) {
#pragma unroll
    for (int m = 0; m < 4; m++) {
      gload16(ga0 + (32 * m) * EMB + k0, la0 + m * 4096);
      gload16(gb0 + (32 * m) * EMB + k0, lb0 + m * 4096);
    }
    __syncthreads();
    u16x8 af[4][2], bfr[4][2];
#pragma unroll
    for (int hh = 0; hh < 2; hh++) {
      const int pc = ((hh * 4 + lg) ^ gfr) * 16;
#pragma unroll
      for (int mi = 0; mi < 4; mi++)
        af[mi][hh] =
            *(const u16x8*)((char*)Al + (wr * 64 + mi * 16 + lr) * 128 + pc);
#pragma unroll
      for (int ni = 0; ni < 4; ni++)
        bfr[ni][hh] =
            *(const u16x8*)((char*)Bl + (wc * 64 + ni * 16 + lr) * 128 + pc);
    }
#pragma unroll
    for (int hh = 0; hh < 2; hh++)
#pragma unroll
      for (int mi = 0; mi < 4; mi++)
#pragma unroll
        for (int ni = 0; ni < 4; ni++)
          acc[mi][ni] = __builtin_amdgcn_mfma_f32_16x16x32_bf16(
              asbf(af[mi][hh]), asbf(bfr[ni][hh]), acc[mi][ni], 0, 0, 0);
    __syncthreads();
  }

#pragma unroll
  for (int mi = 0; mi < 4; mi++) {
    const int lmb = wr * 64 + mi * 16 + lg * 4;
#pragma unroll
    for (int ni = 0; ni < 4; ni++) {
      const int ln = wc * 64 + ni * 16 + lr;
      const int n = n0 + ln;
      const float bv_ = bias[n];
      const int h = n >> 6, d = n & 63;
#pragma unroll
      for (int r = 0; r < 4; r++) {
        const int m = m0 + lmb + r;
        const int b = m >> 11, t = m & 2047;
        float v = acc[mi][ni][r] + bv_;
        if (seg == 0) {
          v *= 0.18033688011f;  // (1/sqrt(64)) * log2(e): exp2-domain scores
          Q[(((b * NHEADS + h) * TT) + t) * HD + d] = cvt(v);
        } else if (seg == 1) {
          K[(((b * NHEADS + h) * TT) + t) * HD + d] = cvt(v);
        } else {
          Vt[(((b * NHEADS + h) * HD) + d) * TT + t] = cvt(v);
        }
      }
    }
  }
}

// ---------- causal flash attention ----------
// r8 structure (512 thr, 8 waves, 64-row pairing, KVBLK=64, swapped QK^T
// in-register P, defer-max, exp2) + T4 counted-vmcnt triple buffer:
// issue tile t+2 after barrier t; wait vmcnt(2) (not 0) + raw s_barrier.
// Per-wave: 2 loads/tile; at iter t outstanding <= 4 (t's 2 + t+1's 2);
// vmcnt(2) retires t's. Wait-then-barrier publishes all waves' writes.
// Buf (t+2)%3 rewritten only after barrier t = after all compute t-1.
__global__ __launch_bounds__(512) void k_attn(const u16* __restrict__ Q,
                                              const u16* __restrict__ Kg,
                                              const u16* __restrict__ Vt,
                                              u16* __restrict__ AO) {
  __shared__ u16 Kl[3][64 * 64];   // 8KB x3
  __shared__ u16 Vl[3][64 * 64];   // 8KB x3
  const int tid = threadIdx.x;
  const int lane = tid & 63;
  const int w = tid >> 6;          // 0..7
  const int lr = lane & 15, lg = lane >> 4;
  const int bh = blockIdx.x;       // 0..31
  const int pair = blockIdx.y;     // 0..15; pair 0 dispatches first (longest)
  const int lo = pair, hi = 31 - pair;
  const int qblk = (w < 4) ? hi : lo;      // this wave's 64-row q-block
  const int myend = qblk;                  // last k-tile index for this wave
  const int q0 = qblk * 64 + (w & 3) * 16;
  const u16* __restrict__ Qh = Q + bh * TT * HD;
  const u16* __restrict__ Kh = Kg + bh * TT * HD;
  const u16* __restrict__ Vh = Vt + bh * HD * TT;

  // staging: thread t covers row t>>3, phys chunk t&7 of the 64x128B tile.
  // sc = (t&7) ^ g(row); g(row)=(row&3)|(((row>>3)&1)<<2).
  const int srow = tid >> 3;  // 0..63
  const int sgz = ((tid >> 3) & 3) | (((tid >> 6) & 1) << 2);
  const int sc = (tid & 7) ^ sgz;

  u16x8 qf[2];
  qf[0] = *(const u16x8*)&Qh[(q0 + lr) * HD + lg * 8];
  qf[1] = *(const u16x8*)&Qh[(q0 + lr) * HD + 32 + lg * 8];

  f32x4 accO[4];
#pragma unroll
  for (int i = 0; i < 4; i++) accO[i] = (f32x4){0.f, 0.f, 0.f, 0.f};
  float mst = -__builtin_inff();  // per-lane: running max of row q0+lr
  float lsum = 0.f;               // per-lane partial denominator

  const int nkt = hi + 1;  // block-uniform loop count (>= 17)

  // prologue: stage tiles 0 and 1
  gload16(Kh + srow * HD + sc * 8, (char*)Kl[0] + w * 1024);
  gload16(Vh + srow * TT + sc * 8, (char*)Vl[0] + w * 1024);
  gload16(Kh + (64 + srow) * HD + sc * 8, (char*)Kl[1] + w * 1024);
  gload16(Vh + srow * TT + 64 + sc * 8, (char*)Vl[1] + w * 1024);

  for (int kt = 0; kt < nkt; ++kt) {
    const int k0 = kt * 64;
    // counted wait: retire tile kt's 2 loads (t+1's 2 may stay in flight)
    if (kt == nkt - 1)
      asm volatile("s_waitcnt vmcnt(0)" ::: "memory");
    else
      asm volatile("s_waitcnt vmcnt(2)" ::: "memory");
    __builtin_amdgcn_s_barrier();
    __builtin_amdgcn_sched_barrier(0);
    // issue tile kt+2 into buf (kt+2)%3 (= buf of finished tile kt-1)
    if (kt + 2 < nkt) {
      const int kn = k0 + 128;
      const int bn = (kt + 2) % 3;
      gload16(Kh + (kn + srow) * HD + sc * 8, (char*)Kl[bn] + w * 1024);
      gload16(Vh + srow * TT + kn + sc * 8, (char*)Vl[bn] + w * 1024);
    }
    if (kt <= myend) {  // wave-uniform: lo-waves idle past their diagonal
      const char* Kc = (const char*)Kl[kt % 3];
      const char* Vc = (const char*)Vl[kt % 3];

      f32x4 s[4];
#pragma unroll
      for (int n = 0; n < 4; n++) s[n] = (f32x4){0.f, 0.f, 0.f, 0.f};
      __builtin_amdgcn_s_setprio(1);
#pragma unroll
      for (int n = 0; n < 4; n++) {
        // permuted K-row: lane's 16 score cols == PV A-frag slots
        const int kr =
            (lr & 3) + ((n & 1) << 2) + ((lr >> 2) << 3) + ((n >> 1) << 5);
        const int gg = (kr & 3) | (((kr >> 3) & 1) << 2);
#pragma unroll
        for (int dh = 0; dh < 2; dh++) {
          const int bo = ((dh * 4 + lg) ^ gg) << 4;
          u16x8 kf = *(const u16x8*)(Kc + kr * 128 + bo);
          s[n] = __builtin_amdgcn_mfma_f32_16x16x32_bf16(asbf(kf), asbf(qf[dh]),
                                                         s[n], 0, 0, 0);
        }
      }
      __builtin_amdgcn_s_setprio(0);
      if (kt == myend) {  // diagonal tile: causal mask (col > my q-row)
        const int rowq = q0 + lr;
#pragma unroll
        for (int n = 0; n < 4; n++) {
          const int cb = k0 + ((n & 1) << 2) + (lg << 3) + ((n >> 1) << 5);
#pragma unroll
          for (int r = 0; r < 4; r++)
            if (cb + r > rowq) s[n][r] = -__builtin_inff();
        }
      }
      // lane-local row max over this tile's 16 cols
      float m01 = fmaxf(fmaxf(s[0][0], s[0][1]), fmaxf(s[0][2], s[0][3]));
      float m1 = fmaxf(fmaxf(s[1][0], s[1][1]), fmaxf(s[1][2], s[1][3]));
      float m2 = fmaxf(fmaxf(s[2][0], s[2][1]), fmaxf(s[2][2], s[2][3]));
      float m3 = fmaxf(fmaxf(s[3][0], s[3][1]), fmaxf(s[3][2], s[3][3]));
      float lmax = fmaxf(fmaxf(m01, m1), fmaxf(m2, m3));
      // defer-max (log2 domain, THR=11 bits). -inf tile0 forces rescale.
      if (!__all(lmax - mst <= 11.0f)) {
        float rm = lmax;
        rm = fmaxf(rm, __shfl_xor(rm, 16));
        rm = fmaxf(rm, __shfl_xor(rm, 32));
        float mnew = fmaxf(mst, rm);
        float corr = exp2f(mst - mnew);
        lsum *= corr;
        mst = mnew;
#pragma unroll
        for (int r = 0; r < 4; r++) {  // corr for accO's q-row (lg*4+r)
          float ca = __shfl(corr, 20 * lg + r);
#pragma unroll
          for (int dt = 0; dt < 4; dt++) accO[dt][r] *= ca;
        }
      }
      // P in-register: p[n][r] are exactly PV A-frag slots
      float p[4][4];
      float ls = 0.f;
#pragma unroll
      for (int n = 0; n < 4; n++)
#pragma unroll
        for (int r = 0; r < 4; r++) {
          p[n][r] = exp2f(s[n][r] - mst);
          ls += p[n][r];
        }
      lsum += ls;
      u16x8 a1, a2;
#pragma unroll
      for (int r = 0; r < 4; r++) {
        a1[r] = cvt(p[0][r]);
        a1[4 + r] = cvt(p[1][r]);
        a2[r] = cvt(p[2][r]);
        a2[4 + r] = cvt(p[3][r]);
      }
      __builtin_amdgcn_s_setprio(1);
#pragma unroll
      for (int dt = 0; dt < 4; dt++) {
        const int row = dt * 16 + lr;
        const int gg = (row & 3) | (((row >> 3) & 1) << 2);
        const int bo0 = ((lg ^ gg) << 4);
        const int bo1 = (((4 + lg) ^ gg) << 4);
        u16x8 vf0 = *(const u16x8*)(Vc + row * 128 + bo0);
        u16x8 vf1 = *(const u16x8*)(Vc + row * 128 + bo1);
        accO[dt] = __builtin_amdgcn_mfma_f32_16x16x32_bf16(asbf(a1), asbf(vf0),
                                                           accO[dt], 0, 0, 0);
        accO[dt] = __builtin_amdgcn_mfma_f32_16x16x32_bf16(asbf(a2), asbf(vf1),
                                                           accO[dt], 0, 0, 0);
      }
      __builtin_amdgcn_s_setprio(0);
    }
    // no end-of-iteration sync: next iteration's wait+barrier handles it
  }
  // denominator: reduce the 4 lanes sharing this q-row, then redistribute
  float t = lsum;
  t += __shfl_xor(t, 16);
  t += __shfl_xor(t, 32);
  float rinv = 1.0f / t;
  float ra[4];
#pragma unroll
  for (int r = 0; r < 4; r++) ra[r] = __shfl(rinv, 20 * lg + r);
  const int b = bh >> 4, h = bh & 15;
#pragma unroll
  for (int dt = 0; dt < 4; dt++)
#pragma unroll
    for (int r = 0; r < 4; r++) {
      const int row = q0 + lg * 4 + r;
      const int d = h * 64 + dt * 16 + lr;
      AO[(b * TT + row) * EMB + d] = cvt(accO[dt][r] * ra[r]);
    }
}

// ---------- output projection GEMM (BK=64, fp32 out + bias) ----------
__global__ __launch_bounds__(256) void k_gemm_out(const u16* __restrict__ AO,
                                                  const u16* __restrict__ WoT,
                                                  const float* __restrict__ bo,
                                                  float* __restrict__ out) {
  __shared__ u16 Al[128 * 64];
  __shared__ u16 Bl[128 * 64];
  const int tid = threadIdx.x;
  const int lane = tid & 63;
  const int w = tid >> 6;
  const int wr = w >> 1, wc = w & 1;
  const int lr = lane & 15, lg = lane >> 4;
  const int m0 = blockIdx.x * 128;
  const int n0 = blockIdx.y * 128;

  f32x4 acc[4][4];
#pragma unroll
  for (int i = 0; i < 4; i++)
#pragma unroll
    for (int j = 0; j < 4; j++) acc[i][j] = (f32x4){0.f, 0.f, 0.f, 0.f};

  const int srow = tid >> 3;
  const int sgz = ((tid >> 3) & 3) | (((tid >> 6) & 1) << 2);
  const int sc = (tid & 7) ^ sgz;
  const u16* ga0 = AO + (m0 + srow) * EMB + sc * 8;
  const u16* gb0 = WoT + (n0 + srow) * EMB + sc * 8;
  char* la0 = (char*)Al + w * 1024;
  char* lb0 = (char*)Bl + w * 1024;
  const int gfr = (lr & 3) | (((lr >> 3) & 1) << 2);

  for (int k0 = 0; k0 < EMB; k0 += 64) {
#pragma unroll
    for (int m = 0; m < 4; m++) {
      gload16(ga0 + (32 * m) * EMB + k0, la0 + m * 4096);
      gload16(gb0 + (32 * m) * EMB + k0, lb0 + m * 4096);
    }
    __syncthreads();
    u16x8 af[4][2], bfr[4][2];
#pragma unroll
    for (int hh = 0; hh < 2; hh++) {
      const int pc = ((hh * 4 + lg) ^ gfr) * 16;
#pragma unroll
      for (int mi = 0; mi < 4; mi++)
        af[mi][hh] =
            *(const u16x8*)((char*)Al + (wr * 64 + mi * 16 + lr) * 128 + pc);
#pragma unroll
      for (int ni = 0; ni < 4; ni++)
        bfr[ni][hh] =
            *(const u16x8*)((char*)Bl + (wc * 64 + ni * 16 + lr) * 128 + pc);
    }
#pragma unroll
    for (int hh = 0; hh < 2; hh++)
#pragma unroll
      for (int mi = 0; mi < 4; mi++)
#pragma unroll
        for (int ni = 0; ni < 4; ni++)
          acc[mi][ni] = __builtin_amdgcn_mfma_f32_16x16x32_bf16(
              asbf(af[mi][hh]), asbf(bfr[ni][hh]), acc[mi][ni], 0, 0, 0);
    __syncthreads();
  }

#pragma unroll
  for (int mi = 0; mi < 4; mi++) {
    const int lmb = wr * 64 + mi * 16 + lg * 4;
#pragma unroll
    for (int ni = 0; ni < 4; ni++) {
      const int ln = wc * 64 + ni * 16 + lr;
      const int n = n0 + ln;
      const float bv_ = bo[n];
#pragma unroll
      for (int r = 0; r < 4; r++) {
        const int m = m0 + lmb + r;
        out[m * EMB + n] = acc[mi][ni][r] + bv_;
      }
    }
  }
}

// ---------- launch ----------
extern "C" void kernel_launch(void* const* d_in, const int* in_sizes, int n_in,
                              void* d_out, int out_size, void* d_ws,
                              size_t ws_size, hipStream_t stream) {
  const float* x = (const float*)d_in[0];
  const float* Wq = (const float*)d_in[1];
  const float* bq = (const float*)d_in[2];
  const float* Wk = (const float*)d_in[3];
  const float* bk = (const float*)d_in[4];
  const float* Wv = (const float*)d_in[5];
  const float* bv = (const float*)d_in[6];
  const float* Wo = (const float*)d_in[7];
  const float* bo = (const float*)d_in[8];
  float* out = (float*)d_out;

  char* ws = (char*)d_ws;
  u16* xb = (u16*)ws;                      // 8 MB (reused as AO)
  u16* WqT = (u16*)(ws + (8u << 20));      // 2 MB
  u16* WkT = (u16*)(ws + (10u << 20));     // 2 MB
  u16* WvT = (u16*)(ws + (12u << 20));     // 2 MB
  u16* WoT = (u16*)(ws + (14u << 20));     // 2 MB
  u16* Qb = (u16*)(ws + (16u << 20));      // 8 MB
  u16* Kb = (u16*)(ws + (24u << 20));      // 8 MB
  u16* Vtb = (u16*)(ws + (32u << 20));     // 8 MB (total 40 MB)
  u16* AO = xb;

  k_prep<<<6144, 256, 0, stream>>>(x, xb, Wq, Wk, Wv, Wo, WqT, WkT, WvT, WoT);
  k_gemm_qkv<<<dim3(32, 24), 256, 0, stream>>>(xb, WqT, WkT, WvT, bq, bk, bv,
                                               Qb, Kb, Vtb);
  k_attn<<<dim3(32, 16), 512, 0, stream>>>(Qb, Kb, Vtb, AO);
  k_gemm_out<<<dim3(32, 8), 256, 0, stream>>>(AO, WoT, bo, out);
}